// Round 7
// baseline (594.861 us; speedup 1.0000x reference)
//
#include <hip/hip_runtime.h>
#include <stdint.h>

typedef unsigned short u16;
typedef unsigned int u32;
typedef short bf16x8 __attribute__((ext_vector_type(8)));
typedef float f32x4 __attribute__((ext_vector_type(4)));
typedef u16 u16x4 __attribute__((ext_vector_type(4)));

#define DEV __device__ __forceinline__

DEV float bf2f(u16 u) { union { float f; u32 i; } x; x.i = ((u32)u) << 16; return x.f; }
DEV u16 f2bf(float f) {
  union { float f; u32 i; } x; x.f = f;
  u32 i = x.i;
  u32 r = (i + 0x7fffu + ((i >> 16) & 1u)) >> 16;  // RTNE
  return (u16)r;
}

// async global->LDS, 16B per lane. lds base must be wave-uniform; HW adds lane*16.
DEV void gl_lds16(const u16* g, u16* l) {
  __builtin_amdgcn_global_load_lds((const __attribute__((address_space(1))) u32*)g,
                                   (__attribute__((address_space(3))) u32*)l, 16, 0, 0);
}

// ---------------- prep: x cast + all weight transposes, ONE launch ----------------
__global__ __launch_bounds__(256) void prep(const float* __restrict__ x,
                                            const float* __restrict__ W_DKV,
                                            const float* __restrict__ W_UK,
                                            const float* __restrict__ W_UV,
                                            const float* __restrict__ W_DQ,
                                            const float* __restrict__ W_UQ,
                                            const float* __restrict__ W_QR,
                                            const float* __restrict__ W_KR,
                                            const float* __restrict__ W_O,
                                            u16* __restrict__ xb,
                                            u16* __restrict__ WtDKVQ,   // 2048 x 2048 (DKV|DQ)
                                            u16* __restrict__ WtUKV,    // 7168 x 1024 (UK|UV|UQ|QR)
                                            u16* __restrict__ WtKR,     // 64 x 2048
                                            u16* __restrict__ WtO) {
  __shared__ float tile[64][65];
  const int tid = threadIdx.x;
  int bid = blockIdx.x;

  if (bid < 4096) {   // cast x -> bf16, 4 float4 per thread
#pragma unroll
    for (int it = 0; it < 4; ++it) {
      int i = bid * 1024 + it * 256 + tid;
      float4 v = ((const float4*)x)[i];
      u16x4 o;
      o.x = f2bf(v.x); o.y = f2bf(v.y); o.z = f2bf(v.z); o.w = f2bf(v.w);
      ((u16x4*)xb)[i] = o;
    }
    return;
  }
  bid -= 4096;

  const float* W; u16* Wt; int K, N;
  if (bid < 512)        { W = W_DKV; Wt = WtDKVQ;                K = 2048; N = 1024; }
  else if (bid < 1024)  { W = W_DQ;  Wt = WtDKVQ + 1024 * 2048;  K = 2048; N = 1024; bid -= 512; }
  else if (bid < 1536)  { W = W_UK;  Wt = WtUKV;                 K = 1024; N = 2048; bid -= 1024; }
  else if (bid < 2048)  { W = W_UV;  Wt = WtUKV + 2048 * 1024;   K = 1024; N = 2048; bid -= 1536; }
  else if (bid < 2560)  { W = W_UQ;  Wt = WtUKV + 4096 * 1024;   K = 1024; N = 2048; bid -= 2048; }
  else if (bid < 2816)  { W = W_QR;  Wt = WtUKV + 6144 * 1024;   K = 1024; N = 1024; bid -= 2560; }
  else if (bid < 2848)  { W = W_KR;  Wt = WtKR;                  K = 2048; N = 64;   bid -= 2816; }
  else                  { W = W_O;   Wt = WtO;                   K = 2048; N = 2048; bid -= 2848; }

  const int gx = N >> 6;
  const int n0 = (bid % gx) * 64;
  const int k0 = (bid / gx) * 64;
#pragma unroll
  for (int i = 0; i < 16; ++i) {
    int idx = tid + i * 256;
    int r = idx >> 6, c = idx & 63;             // r: k-off, c: n-off
    tile[r][c] = W[(size_t)(k0 + r) * N + n0 + c];
  }
  __syncthreads();
#pragma unroll
  for (int i = 0; i < 16; ++i) {
    int idx = tid + i * 256;
    int r = idx >> 6, c = idx & 63;             // r: n-off, c: k-off
    Wt[(size_t)(n0 + r) * K + k0 + c] = f2bf(tile[c][r]);
  }
}

DEV void ep_set(u16* E, int i, float v) { E[i] = f2bf(v); }
DEV void ep_set(float* E, int i, float v) { E[i] = v; }

// ---------------- GEMM 256x256 8-phase (T2+T3+T4+T5): C = A(MxK) * Bt(NxK)^T ----------------
// KIND 0: plain C, 2-D grid.  KIND 2 (G2+G3 merged + KR head): 1-D grid of 928.
//   first 32 blocks: kr = A2(xb) @ B2(WtKR)^T (latency-bound, runs under round 1).
//   main 896: n0<2048 -> C=kc; [2048,4096) -> X1=Vt TRANSPOSED; >=4096 -> X2=qcr, A+1024.
// Block mapping: XCD-chunked + 4-m-inner (concurrent set = 4m x 8n). Counted
// vmcnt(4) once per K-tile, raw s_barrier, read-side XOR swizzle with
// pre-swizzled global source (both-sides rule), setprio around MFMA.
template <typename OT, int KIND>
__global__ __launch_bounds__(512, 2) void gemm256(const u16* __restrict__ A, int lda,
                                                  const u16* __restrict__ Bt,
                                                  OT* __restrict__ C, int ldc, int K,
                                                  u16* __restrict__ X1, u16* __restrict__ X2,
                                                  const u16* __restrict__ A2,
                                                  const u16* __restrict__ B2,
                                                  u16* __restrict__ C2) {
  __shared__ u16 smem[65536];   // 128KB: buf[t&1]{ A[2][256][32] | B[2][256][32] }
  const int tid = threadIdx.x;
  const int lane = tid & 63;
  const int w = tid >> 6;       // 0..7
  const int wm = w >> 2;        // 0..1 (M)
  const int wn = w & 3;         // 0..3 (N)
  const int quad = lane >> 4;
  const int l15 = lane & 15;
  const int cs = quad ^ ((l15 >> 1) & 3);   // swizzled k-chunk for frag reads

  int m0, n0;
  if constexpr (KIND == 2) {
    const int lin2 = blockIdx.x;       // 0..927
    if (lin2 < 32) {
      // ---- KR head blocks: kr = xb @ WtKR^T (M=8192,N=64,K=2048) ----
      const int idx = lin2;            // m-block 0..31
      u16* Ab2 = smem;                 // [2][256*64] u16 (64KB)
      u16* Bb2 = smem + 32768;         // [2][64*64] u16 (16KB)
      const u16* Ag2 = A2 + (size_t)(idx * 256) * 2048;
      auto stg = [&](int t2, int bufi) {
        u16* Ad = Ab2 + bufi * 16384;
        u16* Bd = Bb2 + bufi * 4096;
#pragma unroll
        for (int i = 0; i < 4; ++i) {
          int cb = i * 512 + w * 64;          // wave-uniform
          int c = cb + lane;
          int r = c >> 3, cp = (c & 7) ^ (r & 7);   // pre-swizzled source column
          gl_lds16(Ag2 + (size_t)r * 2048 + t2 * 64 + cp * 8, &Ad[cb * 8]);
        }
        {
          int cb = w * 64;
          int c = cb + lane;
          int r = c >> 3, cp = (c & 7) ^ (r & 7);
          gl_lds16(B2 + (size_t)r * 2048 + t2 * 64 + cp * 8, &Bd[cb * 8]);
        }
      };
      f32x4 acc2[2][4] = {};
      stg(0, 0);
      __syncthreads();
      for (int t2 = 0; t2 < 32; ++t2) {
        int cur = t2 & 1;
        if (t2 + 1 < 32) stg(t2 + 1, cur ^ 1);
        const u16* Ad = Ab2 + cur * 16384;
        const u16* Bd = Bb2 + cur * 4096;
#pragma unroll
        for (int kq = 0; kq < 2; ++kq) {
          bf16x8 bfr[4];
#pragma unroll
          for (int n = 0; n < 4; ++n)
            bfr[n] = *(const bf16x8*)&Bd[(n * 16 + l15) * 64 + ((kq * 4 + quad) ^ (l15 & 7)) * 8];
#pragma unroll
          for (int mt = 0; mt < 2; ++mt) {
            bf16x8 afr = *(const bf16x8*)&Ad[(w * 32 + mt * 16 + l15) * 64 + ((kq * 4 + quad) ^ (l15 & 7)) * 8];
#pragma unroll
            for (int n = 0; n < 4; ++n)
              acc2[mt][n] = __builtin_amdgcn_mfma_f32_16x16x32_bf16(afr, bfr[n], acc2[mt][n], 0, 0, 0);
          }
        }
        __syncthreads();
      }
#pragma unroll
      for (int mt = 0; mt < 2; ++mt)
#pragma unroll
        for (int n = 0; n < 4; ++n)
#pragma unroll
          for (int r = 0; r < 4; ++r)
            C2[(size_t)(idx * 256 + w * 32 + mt * 16 + quad * 4 + r) * 64 + n * 16 + l15] =
                f2bf(acc2[mt][n][r]);
      return;
    }
    // main mapping: c in [0,896), XCD-chunked + 4-m-inner (concurrent = 4m x 8n)
    const int c = lin2 - 32;              // xcd(lin2)=lin2&7=c&7 (32%8==0)
    const int cc = (c & 7) * 112 + (c >> 3);
    const int g4 = cc >> 2;
    n0 = (g4 % 28) * 256;
    m0 = ((g4 / 28) * 4 + (cc & 3)) * 256;
  } else {
    const int nwg = gridDim.x * gridDim.y;
    const int lin = blockIdx.y * gridDim.x + blockIdx.x;
    const int swz = (lin & 7) * (nwg >> 3) + (lin >> 3);
    const int g4 = swz >> 2;
    n0 = (g4 % gridDim.x) * 256;
    m0 = ((g4 / gridDim.x) * 4 + (swz & 3)) * 256;   // requires gridDim.y % 4 == 0
  }

  // staging per-thread geometry: thread covers row rloc, phys chunk tid&3;
  // pre-swizzled source column so linear LDS dest + swizzled read match.
  const int rloc = tid >> 2;                       // 0..127
  const int clog = (tid & 3) ^ ((tid >> 3) & 3);   // pre-swizzled source column
  const u16* Abase = A + ((KIND == 2 && n0 >= 4096) ? 1024 : 0);
  const size_t aoff0 = (size_t)rloc * lda + clog * 8;
  const size_t boff0 = (size_t)rloc * (size_t)K + clog * 8;
  const u16* Ag = Abase + (size_t)m0 * lda;
  const u16* Bg = Bt + (size_t)n0 * K;

  auto stageA = [&](int u, int ks2) {
    u16* dst = smem + (u & 1) * 32768 + ks2 * 8192 + w * 512;
    const u16* s0 = Ag + aoff0 + u * 64 + ks2 * 32;
    gl_lds16(s0, dst);
    gl_lds16(s0 + (size_t)128 * lda, dst + 4096);
  };
  auto stageB = [&](int u, int ks2) {
    u16* dst = smem + (u & 1) * 32768 + 16384 + ks2 * 8192 + w * 512;
    const u16* s0 = Bg + boff0 + u * 64 + ks2 * 32;
    gl_lds16(s0, dst);
    gl_lds16(s0 + (size_t)128 * (size_t)K, dst + 4096);
  };

  f32x4 acc[2][4][4] = {};   // [mq][mt][n], all indices compile-time
  const int nt = K >> 6;

  stageA(0, 0); stageB(0, 0); stageA(0, 1); stageB(0, 1);
  stageA(1, 0); stageB(1, 0);
  asm volatile("s_waitcnt vmcnt(4)" ::: "memory");
  __builtin_amdgcn_s_barrier();

  for (int t = 0; t < nt; ++t) {
    const u16* As_ = smem + (t & 1) * 32768;
    const u16* Bs_ = As_ + 16384;
#pragma unroll
    for (int p = 0; p < 4; ++p) {
      const int ks = p >> 1;
      const int mq = p & 1;
      const u16* Ab = As_ + ks * 8192;
      const u16* Bb = Bs_ + ks * 8192;
      bf16x8 af[4], bf[4];
#pragma unroll
      for (int mt = 0; mt < 4; ++mt)
        af[mt] = *(const bf16x8*)&Ab[(wm * 128 + mq * 64 + mt * 16 + l15) * 32 + cs * 8];
#pragma unroll
      for (int n = 0; n < 4; ++n)
        bf[n] = *(const bf16x8*)&Bb[(wn * 64 + n * 16 + l15) * 32 + cs * 8];
      if (p == 0)      { if (t + 1 < nt) stageA(t + 1, 1); }
      else if (p == 1) { if (t + 1 < nt) stageB(t + 1, 1); }
      else if (p == 2) { if (t + 2 < nt) stageA(t + 2, 0); }
      else             { if (t + 2 < nt) stageB(t + 2, 0); }
      __builtin_amdgcn_s_barrier();
      __builtin_amdgcn_s_setprio(1);
#pragma unroll
      for (int mt = 0; mt < 4; ++mt)
#pragma unroll
        for (int n = 0; n < 4; ++n)
          acc[mq][mt][n] = __builtin_amdgcn_mfma_f32_16x16x32_bf16(af[mt], bf[n], acc[mq][mt][n], 0, 0, 0);
      __builtin_amdgcn_s_setprio(0);
      if (p == 3) asm volatile("s_waitcnt vmcnt(4)" ::: "memory");
      __builtin_amdgcn_s_barrier();
    }
  }
  asm volatile("s_waitcnt vmcnt(0)" ::: "memory");
  __builtin_amdgcn_s_barrier();

  if constexpr (KIND == 2) {
    if (n0 >= 2048 && n0 < 4096) {
      // VMODE: write this quadrant transposed into Vt (b,h,dv,L).
      u16* Ewt = smem + w * 2560;        // 64 * 40 u16 = 5120B per wave
      const int dvb = (n0 - 2048) + wn * 64;
      const int hh = dvb >> 7;
      const int dv0 = dvb & 127;         // 0 or 64
#pragma unroll
      for (int mq = 0; mq < 2; ++mq)
#pragma unroll
        for (int mh = 0; mh < 2; ++mh) {
#pragma unroll
          for (int mi = 0; mi < 2; ++mi)
#pragma unroll
            for (int n = 0; n < 4; ++n)
#pragma unroll
              for (int r = 0; r < 4; ++r)
                Ewt[(n * 16 + l15) * 40 + mi * 16 + quad * 4 + r] = f2bf(acc[mq][mh * 2 + mi][n][r]);
          asm volatile("s_waitcnt lgkmcnt(0)" ::: "memory");
          const int mbase = m0 + wm * 128 + mq * 64 + mh * 32;
          const int b_ = mbase >> 11, l_ = mbase & 2047;
          u16* dstp = X1 + ((size_t)((b_ * 16 + hh) * 128 + dv0 + lane)) * 2048 + l_;
          const u16* srcp = &Ewt[lane * 40];
#pragma unroll
          for (int k2 = 0; k2 < 4; ++k2)
            *(uint4*)&dstp[k2 * 8] = *(const uint4*)&srcp[k2 * 8];
          asm volatile("s_waitcnt lgkmcnt(0)" ::: "memory");
        }
      return;
    }
  }

  // normal epilogue: wide stores via per-wave LDS region (16 rows x 64 cols per pass)
  OT* Cc = C; int ldcc = ldc, col0 = n0;
  if constexpr (KIND == 2) {
    if (n0 >= 4096) { Cc = (OT*)X2; ldcc = 3072; col0 = n0 - 4096; }
  }
  OT* Ew = ((OT*)smem) + w * 1024;
#pragma unroll
  for (int mq = 0; mq < 2; ++mq) {
#pragma unroll
    for (int mt = 0; mt < 4; ++mt) {
#pragma unroll
      for (int n = 0; n < 4; ++n)
#pragma unroll
        for (int r = 0; r < 4; ++r)
          ep_set(Ew, (quad * 4 + r) * 64 + n * 16 + l15, acc[mq][mt][n][r]);
      asm volatile("s_waitcnt lgkmcnt(0)" ::: "memory");
#pragma unroll
      for (int it2 = 0; it2 < 4; ++it2) {
        int row_i = it2 * 4 + quad;
        size_t off = (size_t)(m0 + wm * 128 + mq * 64 + mt * 16 + row_i) * ldcc + col0 + wn * 64 + l15 * 4;
        if constexpr (sizeof(OT) == 2) {
          *(u16x4*)&Cc[off] = *(const u16x4*)&Ew[row_i * 64 + l15 * 4];
        } else {
          *(float4*)&Cc[off] = *(const float4*)&Ew[row_i * 64 + l15 * 4];
        }
      }
      asm volatile("s_waitcnt lgkmcnt(0)" ::: "memory");  // Ew reads done before rewrite
    }
  }
}

// ---------------- build k: rope + concat + L2-normalize, one wave per (token, head) ----------------
__global__ __launch_bounds__(256) void build_k(const u16* __restrict__ kc,   // (B*L, 2048)
                                               const u16* __restrict__ krr,  // (B*L, 64)
                                               u16* __restrict__ kn) {
  const int wid = blockIdx.x * 4 + (threadIdx.x >> 6);
  const int lane = threadIdx.x & 63;
  const int token = wid >> 4;
  const int h = wid & 15;
  const int b = token >> 11;
  const int l = token & 2047;
  float v0 = bf2f(kc[(size_t)token * 2048 + h * 128 + lane]);
  float v1 = bf2f(kc[(size_t)token * 2048 + h * 128 + 64 + lane]);
  int j = lane & 31;
  float freq = __expf((float)j * -0.28782313662425574f);   // 10000^(-j/32)
  float ang = (float)l * freq;
  float cs = __cosf(ang), sn = __sinf(ang);
  float xr = bf2f(krr[(size_t)token * 64 + lane]);
  float xo = bf2f(krr[(size_t)token * 64 + (lane ^ 32)]);
  float v2 = (lane < 32) ? (xr * cs - xo * sn) : (xr * cs + xo * sn);
  float ss = v0 * v0 + v1 * v1 + v2 * v2;
#pragma unroll
  for (int off = 1; off < 64; off <<= 1) ss += __shfl_xor(ss, off, 64);
  float scale = 1.0f / fmaxf(sqrtf(ss), 1e-12f);
  u16* out = kn + (((size_t)(b * 16 + h) * 2048) + l) * 192;
  out[lane] = f2bf(v0 * scale);
  out[64 + lane] = f2bf(v1 * scale);
  out[128 + lane] = f2bf(v2 * scale);
}

// ---------------- flash attention (causal), 512 thr, balanced pairing, fused Q-build ----------------
// P path: proven C-layout scatter + ds_read_b128 (round-4). Wave-uniform causal
// skip (nomask) for fully-unmasked KV tiles.
__global__ __launch_bounds__(512, 2) void flash_attn(const u16* __restrict__ qcr, // (B*L, 3072): qc|qr
                                                     const u16* __restrict__ Kn,  // (B,H,L,192)
                                                     const u16* __restrict__ Vt,  // (B,H,128,L)
                                                     const float* __restrict__ s_qk,
                                                     u16* __restrict__ O) {       // (B,L,2048)
  constexpr int L = 2048, DQK = 192, KVB = 64;
  constexpr int PSTR = 72;
  __shared__ u16 smem[59392];          // Ks[2][64*192] | Vs[2][128*64] | Ps[8*32*72] = 118784 B
  u16* KsBuf = smem;                   // 2 x 12288 u16
  u16* VsBuf = smem + 24576;           // 2 x 8192 u16
  u16* Ps    = smem + 40960;           // 18432 u16
  const int tid = threadIdx.x;
  const int lane = tid & 63;
  const int w = tid >> 6;       // 0..7, q-row group (32 rows each)
  const int quad = lane >> 4;
  const int l15 = lane & 15;
  const int lin = blockIdx.x;
  const int xcd = lin & 7;
  const int g = lin >> 3;         // 0..31
  const int bh = ((g >> 2) << 3) | xcd;
  const int pairIdx = g & 3;      // qtA = 7-pairIdx, qtB = pairIdx -> 36 tiles each
  const int b = bh >> 4, h = bh & 15;
  const float SMAX = s_qk[0];     // upper bound on every score (unit q,k; q pre-scaled)

  const u16* Kg = Kn + (size_t)bh * L * DQK;
  const u16* Vg = Vt + (size_t)bh * 128 * L;

  // stage address precompute (constant across kt)
  int koffs[3], kdsts[3], voffs[2], vdsts[2];
#pragma unroll
  for (int it = 0; it < 3; ++it) {
    int p = it * 512 + w * 64 + lane;
    int r = p / 24, cp = p % 24;
    koffs[it] = r * DQK + (cp ^ (r & 7)) * 8;
    kdsts[it] = (it * 512 + w * 64) * 8;
  }
#pragma unroll
  for (int it = 0; it < 2; ++it) {
    int q = (it + 3) * 512 + w * 64 + lane - 1536;
    int dv = q >> 3, cp = q & 7;
    voffs[it] = dv * L + (cp ^ (dv & 7)) * 8;
    vdsts[it] = ((it + 3) * 512 + w * 64 - 1536) * 8;
  }

  auto stage = [&](int kt2, int bufi) {
    u16* KsB = KsBuf + bufi * 12288;
    u16* VsB = VsBuf + bufi * 8192;
    const u16* Kt = Kg + (size_t)(kt2 * KVB) * DQK;
    const u16* Vtb = Vg + kt2 * KVB;
#pragma unroll
    for (int it = 0; it < 3; ++it) gl_lds16(Kt + koffs[it], &KsB[kdsts[it]]);
#pragma unroll
    for (int it = 0; it < 2; ++it) gl_lds16(Vtb + voffs[it], &VsB[vdsts[it]]);
  };

  bf16x8 ones;
#pragma unroll
  for (int j = 0; j < 8; ++j) ones[j] = (short)0x3F80;   // bf16 1.0

  for (int qp = 0; qp < 2; ++qp) {
    const int qt = (qp == 0) ? (7 - pairIdx) : pairIdx;

    // ---- fused Q-build: load raw qc|qr, rope kd4/5, L2-normalize, scale by s_qk ----
    bf16x8 qf[2][6];
#pragma unroll
    for (int mt = 0; mt < 2; ++mt) {
      const int row = qt * 256 + w * 32 + mt * 16 + l15;
      const u16* qr_ = qcr + (size_t)(b * 2048 + row) * 3072;
#pragma unroll
      for (int kd = 0; kd < 4; ++kd)
        qf[mt][kd] = *(const bf16x8*)&qr_[h * 128 + kd * 32 + quad * 8];
      bf16x8 a4 = *(const bf16x8*)&qr_[2048 + h * 64 + quad * 8];
      bf16x8 a5 = *(const bf16x8*)&qr_[2048 + h * 64 + 32 + quad * 8];
      float v4[8], v5[8];
      float ss = 0.f;
#pragma unroll
      for (int e = 0; e < 8; ++e) {
        int j = quad * 8 + e;
        float fr = __expf((float)j * -0.28782313662425574f);
        float ang = (float)row * fr;
        float cs2 = __cosf(ang), sn2 = __sinf(ang);
        float x4 = bf2f((u16)a4[e]), x5 = bf2f((u16)a5[e]);
        v4[e] = x4 * cs2 - x5 * sn2;
        v5[e] = x5 * cs2 + x4 * sn2;
        ss += v4[e] * v4[e] + v5[e] * v5[e];
      }
#pragma unroll
      for (int kd = 0; kd < 4; ++kd)
#pragma unroll
        for (int e = 0; e < 8; ++e) { float xv = bf2f((u16)qf[mt][kd][e]); ss += xv * xv; }
      ss += __shfl_xor(ss, 16, 64);
      ss += __shfl_xor(ss, 32, 64);
      float scale = SMAX / fmaxf(sqrtf(ss), 1e-12f);
#pragma unroll
      for (int kd = 0; kd < 4; ++kd) {
        bf16x8 t = qf[mt][kd];
#pragma unroll
        for (int e = 0; e < 8; ++e) t[e] = (short)f2bf(bf2f((u16)t[e]) * scale);
        qf[mt][kd] = t;
      }
      bf16x8 t4, t5;
#pragma unroll
      for (int e = 0; e < 8; ++e) { t4[e] = (short)f2bf(v4[e] * scale); t5[e] = (short)f2bf(v5[e] * scale); }
      qf[mt][4] = t4; qf[mt][5] = t5;
    }

    f32x4 oacc[2][8] = {};
    f32x4 accL[2] = {};           // running row-sum of P via ones-MFMA

    const int nkv = 4 * (qt + 1);   // 64-key tiles
    stage(0, 0);
    __syncthreads();

    for (int kt = 0; kt < nkv; ++kt) {
      const int cur = kt & 1;
      if (kt + 1 < nkv) stage(kt + 1, cur ^ 1);   // prefetch overlaps compute
      const u16* KsC = KsBuf + cur * 12288;
      const u16* VsC = VsBuf + cur * 8192;

      f32x4 s[2][4] = {};
      __builtin_amdgcn_s_setprio(1);
#pragma unroll
      for (int kd = 0; kd < 6; ++kd) {
#pragma unroll
        for (int nt = 0; nt < 4; ++nt) {
          int row = nt * 16 + l15;
          int cp = (kd * 4 + quad) ^ (l15 & 7);
          bf16x8 bb = *(const bf16x8*)&KsC[row * DQK + cp * 8];
#pragma unroll
          for (int mt = 0; mt < 2; ++mt)
            s[mt][nt] = __builtin_amdgcn_mfma_f32_16x16x32_bf16(qf[mt][kd], bb, s[mt][nt], 0, 0, 0);
        }
      }
      __builtin_amdgcn_s_setprio(0);

      // softmax (static max): wave-uniform nomask skip for fully-unmasked tiles
      const int kbase = kt * KVB;
      const bool nomask = (kbase + KVB - 1) <= (qt * 256 + w * 32);  // wave-uniform
      const int kcol0 = kbase + l15;
      u16* Pw = &Ps[w * 32 * PSTR];
#pragma unroll
      for (int mt = 0; mt < 2; ++mt) {
        const int qrow_base = qt * 256 + w * 32 + mt * 16 + quad * 4;
#pragma unroll
        for (int r = 0; r < 4; ++r)
#pragma unroll
          for (int nt = 0; nt < 4; ++nt) {
            float sv = s[mt][nt][r];
            if (!nomask && (kcol0 + nt * 16 > qrow_base + r)) sv = -1e30f;
            Pw[(mt * 16 + quad * 4 + r) * PSTR + nt * 16 + l15] = f2bf(__expf(sv - SMAX));
          }
      }
      asm volatile("s_waitcnt lgkmcnt(0)" ::: "memory");

      __builtin_amdgcn_s_setprio(1);
      bf16x8 pf[2][2];
#pragma unroll
      for (int mt = 0; mt < 2; ++mt)
#pragma unroll
        for (int kc2 = 0; kc2 < 2; ++kc2) {
          pf[mt][kc2] = *(const bf16x8*)&Pw[(mt * 16 + l15) * PSTR + kc2 * 32 + quad * 8];
          accL[mt] = __builtin_amdgcn_mfma_f32_16x16x32_bf16(pf[mt][kc2], ones, accL[mt], 0, 0, 0);
        }
#pragma unroll
      for (int nt2 = 0; nt2 < 8; ++nt2) {
        const int dv = nt2 * 16 + l15;
#pragma unroll
        for (int kc2 = 0; kc2 < 2; ++kc2) {
          int lc = (kc2 * 4 + quad) ^ (l15 & 7);   // dv&7 == l15&7
          bf16x8 vv = *(const bf16x8*)&VsC[dv * KVB + lc * 8];
#pragma unroll
          for (int mt = 0; mt < 2; ++mt)
            oacc[mt][nt2] = __builtin_amdgcn_mfma_f32_16x16x32_bf16(pf[mt][kc2], vv, oacc[mt][nt2], 0, 0, 0);
        }
      }
      __builtin_amdgcn_s_setprio(0);
      __syncthreads();  // drains prefetch (vmcnt) + frees cur buffer
    }

    float rinv[2][4];
#pragma unroll
    for (int mt = 0; mt < 2; ++mt)
#pragma unroll
      for (int r = 0; r < 4; ++r) rinv[mt][r] = 1.0f / accL[mt][r];
    u16* Ew = smem + w * 2048;
#pragma unroll
    for (int mt = 0; mt < 2; ++mt) {
#pragma unroll
      for (int nt2 = 0; nt2 < 8; ++nt2)
#pragma unroll
        for (int r = 0; r < 4; ++r)
          Ew[(quad * 4 + r) * 128 + nt2 * 16 + l15] = f2bf(oacc[mt][nt2][r] * rinv[mt][r]);
      asm volatile("s_waitcnt lgkmcnt(0)" ::: "memory");
#pragma unroll
      for (int it2 = 0; it2 < 4; ++it2) {
        int row_i = it2 * 4 + quad;
        int lg = qt * 256 + w * 32 + mt * 16 + row_i;
        uint4 v = *(const uint4*)&Ew[row_i * 128 + l15 * 8];
        *(uint4*)&O[((size_t)b * L + lg) * 2048 + h * 128 + l15 * 8] = v;
      }
      asm volatile("s_waitcnt lgkmcnt(0)" ::: "memory");
    }
    __syncthreads();   // protect Ew region before next pass's stage(0,0)
  }
}

// ---------------- launcher ----------------
extern "C" void kernel_launch(void* const* d_in, const int* in_sizes, int n_in,
                              void* d_out, int out_size, void* d_ws, size_t ws_size,
                              hipStream_t stream) {
  const float* x     = (const float*)d_in[0];
  const float* W_DKV = (const float*)d_in[1];
  const float* W_UK  = (const float*)d_in[2];
  const float* W_UV  = (const float*)d_in[3];
  const float* W_DQ  = (const float*)d_in[4];
  const float* W_UQ  = (const float*)d_in[5];
  const float* W_QR  = (const float*)d_in[6];
  const float* W_KR  = (const float*)d_in[7];
  const float* W_O   = (const float*)d_in[8];
  const float* s_qk  = (const float*)d_in[9];

  char* base = (char*)d_ws;
  // static layout (bytes) — high-water ~208.3 MiB:
  u16* xb     = (u16*)(base);                        // [0, 32M)    live to G23 (KR head reads it)
  u16* WtDKVQ = (u16*)(base + (size_t)33554432);     // 2048x2048, dead after G1
  u16* WtUKV  = (u16*)(base + (size_t)42991616);     // 7168x1024, dead after G23
  u16* WtO    = (u16*)(base + (size_t)57671680);     // live to end
  u16* ckvq   = (u16*)(base + (size_t)66060288);     // written G1, read G23, dead after
  u16* kc     = (u16*)(base + (size_t)99614720);     // written G23, read build_k
  u16* Vt     = (u16*)(base + (size_t)133169152);    // written G23 (VMODE), read flash
  u16* qcr    = (u16*)(base + (size_t)166723584);    // written G23, read flash (fused Q)
  u16* kr     = (u16*)(base + (size_t)217055232);    // written G23 (KR head), read build_k
  u16* WtKR   = (u16*)(base + (size_t)218103808);    // 64x2048, read G23 (KR head)
  // aliases:
  u16* kn = (u16*)(base);      // 50.33MB over xb+WtDKVQ+WtUKV-head (all dead before build_k)
  u16* O  = ckvq;              // 32M over ckvq (dead after G23; flash runs after)

  // 1) prep: x cast + all weight transposes (one launch)
  prep<<<7968, 256, 0, stream>>>(x, W_DKV, W_UK, W_UV, W_DQ, W_UQ, W_QR, W_KR, W_O,
                                 xb, WtDKVQ, WtUKV, WtKR, WtO);

  // 2) G1: ckvq = xb @ [W_DKV|W_DQ]^T — exactly 256 blocks (1 round)
  gemm256<u16, 0><<<dim3(8, 32), 512, 0, stream>>>(xb, 2048, WtDKVQ, ckvq, 2048, 2048,
                                                   nullptr, nullptr, nullptr, nullptr, nullptr);

  // 3) G23: KR head (32 blocks, overlaps round 1) + kc | Vt(transposed) | qcr (896 blocks)
  gemm256<u16, 2><<<dim3(928), 512, 0, stream>>>(ckvq, 2048, WtUKV, kc, 2048, 1024,
                                                 Vt, qcr, xb, WtKR, kr);

  // 4) k rope+norm
  build_k<<<32768, 256, 0, stream>>>(kc, kr, kn);

  // 5) attention (fused Q rope+norm), 256 blocks, balanced q-tile pairs
  flash_attn<<<dim3(256), 512, 0, stream>>>(qcr, kn, Vt, s_qk, O);

  // 6) output projection -> fp32 d_out (exactly 256 blocks)
  gemm256<float, 0><<<dim3(8, 32), 512, 0, stream>>>(O, 2048, WtO, (float*)d_out, 2048, 2048,
                                                     nullptr, nullptr, nullptr, nullptr, nullptr);
}